// Round 14
// baseline (65.790 us; speedup 1.0000x reference)
//
#include <hip/hip_runtime.h>
#include <hip/hip_bf16.h>
#include <cstddef>
#include <cstdint>

#define NYV 64
#define NUV 64
#define NHID 512
#define NH2 256
#define NBATCH 64
#define CHUNK 64            // known-good geometry. CHUNK=32 poisoned (R3/R4);
                            // ALL interior mutations banned (R3/R4/R7/R11/R12:
                            // 5 failures incl. provably value-identical transforms).
#define NCHUNK 16
#define XP 520              // Xl row pitch (bf16 units) -> 1040 B, breaks pow2 stride
#define UP 72               // Ul row pitch (bf16 units) -> 144 B

typedef __attribute__((ext_vector_type(8))) short bf16x8;
typedef __attribute__((ext_vector_type(4))) float f32x4;
typedef __attribute__((ext_vector_type(8))) short short8v;

__device__ __forceinline__ uint f2bf(float f) {
    union { __hip_bfloat16 h; ushort s; } u;
    u.h = __float2bfloat16(f);
    return (uint)u.s;
}
__device__ __forceinline__ float bf2f_lo(uint d) {
    union { uint u; float f; } v; v.u = d << 16; return v.f;
}
__device__ __forceinline__ float bf2f_hi(uint d) {
    union { uint u; float f; } v; v.u = d & 0xffff0000u; return v.f;
}

// h-permutation: h' = 2p (real of pair p) / 2p+1 (imag of pair p)
// orig(h') = (h'>>1) + (h'&1)*256

// ---------------------------------------------------------------------------
// FINAL (verified: 65.5-65.6 us, absmax 0.0625, deterministic; R10/R13).
// 2 dispatches, carry_prop folded in:
//  k_scan<false>: stage U -> GEMM1 -> scan from 0 -> chunk-local end states
//                 -> carr. c==0 blocks also compute x0 = y0@Wy2x^T + by2x.
//  k_scan<true> : stage U -> GEMM1 -> seed = per-thread carry chain
//                 (x0 + Lambda^64-weighted carr[cc<c], R2-carry_prop op order)
//                 -> scan -> GEMM2 -> Y.
// ---------------------------------------------------------------------------
template<bool FINAL>
__global__ __launch_bounds__(256) void k_scan(
    const float* __restrict__ U, const float* __restrict__ B,
    const float* __restrict__ lr, const float* __restrict__ li,
    const float* __restrict__ W, const float* __restrict__ bx2y,
    const float* __restrict__ y0, const float* __restrict__ Wy2x,
    const float* __restrict__ by2x,
    float* __restrict__ carr, float* __restrict__ x0buf,
    float* __restrict__ Y)
{
    __shared__ short Xl[CHUNK * XP];   // 66,560 B
    __shared__ short Ul[CHUNK * UP];   //  9,216 B

    const int b  = blockIdx.x;
    const int c  = blockIdx.y;
    const int t0 = c * CHUNK;
    const int tid  = threadIdx.x;
    const int lane = tid & 63;
    const int w    = tid >> 6;          // wave 0..3
    const int lm   = lane & 15;
    const int lg   = lane >> 4;

    // ---- stage U chunk (f32 -> bf16) into Ul[t][u] ----
    {
        const int t = tid >> 2, q = (tid & 3) * 16;
        const float* up = U + ((size_t)(t0 + t) * NBATCH + b) * NUV + q;
        const float4 f0 = *(const float4*)(up + 0);
        const float4 f1 = *(const float4*)(up + 4);
        const float4 f2 = *(const float4*)(up + 8);
        const float4 f3 = *(const float4*)(up + 12);
        short8v s0, s1;
        s0[0]=(short)f2bf(f0.x); s0[1]=(short)f2bf(f0.y);
        s0[2]=(short)f2bf(f0.z); s0[3]=(short)f2bf(f0.w);
        s0[4]=(short)f2bf(f1.x); s0[5]=(short)f2bf(f1.y);
        s0[6]=(short)f2bf(f1.z); s0[7]=(short)f2bf(f1.w);
        s1[0]=(short)f2bf(f2.x); s1[1]=(short)f2bf(f2.y);
        s1[2]=(short)f2bf(f2.z); s1[3]=(short)f2bf(f2.w);
        s1[4]=(short)f2bf(f3.x); s1[5]=(short)f2bf(f3.y);
        s1[6]=(short)f2bf(f3.z); s1[7]=(short)f2bf(f3.w);
        *(short8v*)&Ul[t*UP + q]     = s0;
        *(short8v*)&Ul[t*UP + q + 8] = s1;
    }
    __syncthreads();

    // ---- GEMM1: wave w owns h'-tiles [w*8, w*8+8), all 4 t-tiles ----
    {
        bf16x8 ufrag[4][2];
        #pragma unroll
        for (int nt = 0; nt < 4; ++nt)
            #pragma unroll
            for (int ks = 0; ks < 2; ++ks)
                ufrag[nt][ks] = *(const bf16x8*)&Ul[(nt*16 + lm)*UP + lg*8 + ks*32];

        #pragma unroll
        for (int i = 0; i < 8; ++i) {
            const int mt = w*8 + i;
            const int hp = mt*16 + lm;                    // A-row h'
            const int ho = (hp >> 1) + ((hp & 1) << 8);   // orig h
            bf16x8 a[2];
            #pragma unroll
            for (int ks = 0; ks < 2; ++ks) {
                const float* bp = B + ho*NUV + lg*8 + ks*32;
                const float4 g0 = *(const float4*)(bp);
                const float4 g1 = *(const float4*)(bp + 4);
                bf16x8 t8;
                t8[0]=(short)f2bf(g0.x); t8[1]=(short)f2bf(g0.y);
                t8[2]=(short)f2bf(g0.z); t8[3]=(short)f2bf(g0.w);
                t8[4]=(short)f2bf(g1.x); t8[5]=(short)f2bf(g1.y);
                t8[6]=(short)f2bf(g1.z); t8[7]=(short)f2bf(g1.w);
                a[ks] = t8;
            }
            #pragma unroll
            for (int nt = 0; nt < 4; ++nt) {
                f32x4 acc = {0.f, 0.f, 0.f, 0.f};
                acc = __builtin_amdgcn_mfma_f32_16x16x32_bf16(a[0], ufrag[nt][0], acc, 0, 0, 0);
                acc = __builtin_amdgcn_mfma_f32_16x16x32_bf16(a[1], ufrag[nt][1], acc, 0, 0, 0);
                const int t  = nt*16 + lm;
                const int hb = mt*16 + lg*4;
                uint2 pk;
                pk.x = f2bf(acc[0]) | (f2bf(acc[1]) << 16);
                pk.y = f2bf(acc[2]) | (f2bf(acc[3]) << 16);
                *(uint2*)&Xl[t*XP + hb] = pk;
            }
        }
    }
    __syncthreads();

    // ---- scan: thread p owns complex pair (h'=2p, 2p+1) ----
    {
        const int p = tid;
        const float Lr = lr[p], Li = li[p];
        float x1, x2;
        if (FINAL) {
            // seed = carry chain (R2 carry_prop op order -> bit-identical seeds)
            const float2 x0v = *(const float2*)(x0buf + (size_t)b*NHID + 2*p);
            x1 = x0v.x; x2 = x0v.y;
            float cr = Lr, ci = Li;           // Lambda^64 by 6 squarings
            #pragma unroll
            for (int k = 0; k < 6; ++k) {
                const float nr = cr*cr - ci*ci;
                const float ni = 2.f*cr*ci;
                cr = nr; ci = ni;
            }
            for (int cc = 0; cc < c; ++cc) {
                const float2 le = *(const float2*)(carr + ((size_t)cc*NBATCH + b)*NHID + 2*p);
                const float n1 = cr*x1 - ci*x2 + le.x;
                const float n2 = ci*x1 + cr*x2 + le.y;
                x1 = n1; x2 = n2;
            }
        } else { x1 = 0.f; x2 = 0.f; }
        #pragma unroll 8
        for (int t = 0; t < CHUNK; ++t) {
            const uint d = *(const uint*)&Xl[t*XP + 2*p];
            const float n1 = fmaf(Lr, x1, fmaf(-Li, x2, bf2f_lo(d)));
            const float n2 = fmaf(Li, x1, fmaf( Lr, x2, bf2f_hi(d)));
            x1 = n1; x2 = n2;
            if (FINAL) {
                const uint pk = f2bf(x1) | (f2bf(x2) << 16);
                *(uint*)&Xl[t*XP + 2*p] = pk;
            }
        }
        if (!FINAL) {
            float2* cp = (float2*)(carr + ((size_t)c*NBATCH + b)*NHID + 2*p);
            *cp = make_float2(x1, x2);
        }
    }

    if constexpr (!FINAL) {
        // ---- x0 for batch b (c==0 blocks only) ----
        if (c == 0) {
            const int p = tid;
            float x1 = by2x[p], x2 = by2x[p + NH2];
            #pragma unroll 8
            for (int yv = 0; yv < NYV; ++yv) {
                const float y0v = y0[b * NYV + yv];
                x1 = fmaf(y0v, Wy2x[p * NYV + yv], x1);
                x2 = fmaf(y0v, Wy2x[(p + NH2) * NYV + yv], x2);
            }
            *(float2*)(x0buf + (size_t)b * NHID + 2 * p) = make_float2(x1, x2);
        }
    }

    if constexpr (FINAL) {
        __syncthreads();
        // ---- GEMM2: wave w owns y-tile w; 4 t-tiles; K = 512 ----
        const int y = w*16 + lm;
        const float bias = bx2y[y];
        f32x4 acc2[4];
        #pragma unroll
        for (int mt = 0; mt < 4; ++mt) acc2[mt] = (f32x4){bias, bias, bias, bias};

        #pragma unroll
        for (int ks = 0; ks < 16; ++ks) {
            const int p0 = lg*4 + ks*16;
            const float4 wr = *(const float4*)(W + (size_t)y*NHID + p0);
            const float4 wi = *(const float4*)(W + (size_t)y*NHID + NH2 + p0);
            bf16x8 bf;
            bf[0]=(short)f2bf(wr.x); bf[1]=(short)f2bf(wi.x);
            bf[2]=(short)f2bf(wr.y); bf[3]=(short)f2bf(wi.y);
            bf[4]=(short)f2bf(wr.z); bf[5]=(short)f2bf(wi.z);
            bf[6]=(short)f2bf(wr.w); bf[7]=(short)f2bf(wi.w);
            const int kb = lg*8 + ks*32;
            #pragma unroll
            for (int mt = 0; mt < 4; ++mt) {
                const bf16x8 xa = *(const bf16x8*)&Xl[(mt*16 + lm)*XP + kb];
                acc2[mt] = __builtin_amdgcn_mfma_f32_16x16x32_bf16(xa, bf, acc2[mt], 0, 0, 0);
            }
        }
        #pragma unroll
        for (int mt = 0; mt < 4; ++mt) {
            #pragma unroll
            for (int r = 0; r < 4; ++r) {
                const int t = mt*16 + lg*4 + r;
                Y[((size_t)(t0 + t)*NBATCH + b)*NYV + y] = acc2[mt][r];
            }
        }
    }
}

extern "C" void kernel_launch(void* const* d_in, const int* in_sizes, int n_in,
                              void* d_out, int out_size, void* d_ws, size_t ws_size,
                              hipStream_t stream) {
    const float* y0   = (const float*)d_in[0];
    const float* U    = (const float*)d_in[1];
    const float* lr   = (const float*)d_in[2];
    const float* li   = (const float*)d_in[3];
    const float* B    = (const float*)d_in[4];
    const float* Wy2x = (const float*)d_in[5];
    const float* by2x = (const float*)d_in[6];
    const float* Wx2y = (const float*)d_in[7];
    const float* bx2y = (const float*)d_in[8];
    float* Y    = (float*)d_out;
    char* ws = (char*)d_ws;
    float* carr  = (float*)(ws);                    // chunk-local end states, 2 MB
    float* x0buf = (float*)(ws + (2u<<20));         // x0 per batch, 128 KB

    dim3 grid(NBATCH, NCHUNK);
    k_scan<false><<<grid, 256, 0, stream>>>(U, B, lr, li, Wx2y, bx2y,
                                            y0, Wy2x, by2x, carr, x0buf, Y);
    k_scan<true ><<<grid, 256, 0, stream>>>(U, B, lr, li, Wx2y, bx2y,
                                            y0, Wy2x, by2x, carr, x0buf, Y);
}

// Round 15
// 65.738 us; speedup vs baseline: 1.0008x; 1.0008x over previous
//
#include <hip/hip_runtime.h>
#include <hip/hip_bf16.h>
#include <cstddef>
#include <cstdint>

#define NYV 64
#define NUV 64
#define NHID 512
#define NH2 256
#define NBATCH 64
#define CHUNK 64            // known-good geometry. CHUNK=32 poisoned (R3/R4);
                            // ALL interior mutations banned (R3/R4/R7/R11/R12:
                            // 5 failures incl. provably value-identical transforms).
#define NCHUNK 16
#define XP 520              // Xl row pitch (bf16 units) -> 1040 B, breaks pow2 stride
#define UP 72               // Ul row pitch (bf16 units) -> 144 B

typedef __attribute__((ext_vector_type(8))) short bf16x8;
typedef __attribute__((ext_vector_type(4))) float f32x4;
typedef __attribute__((ext_vector_type(8))) short short8v;

__device__ __forceinline__ uint f2bf(float f) {
    union { __hip_bfloat16 h; ushort s; } u;
    u.h = __float2bfloat16(f);
    return (uint)u.s;
}
__device__ __forceinline__ float bf2f_lo(uint d) {
    union { uint u; float f; } v; v.u = d << 16; return v.f;
}
__device__ __forceinline__ float bf2f_hi(uint d) {
    union { uint u; float f; } v; v.u = d & 0xffff0000u; return v.f;
}

// h-permutation: h' = 2p (real of pair p) / 2p+1 (imag of pair p)
// orig(h') = (h'>>1) + (h'&1)*256

// ---------------------------------------------------------------------------
// FINAL (verified: 65.5-65.8 us, absmax 0.0625, deterministic; R10/R13/R14).
// 2 dispatches, carry_prop folded in:
//  k_scan<false>: stage U -> GEMM1 -> scan from 0 -> chunk-local end states
//                 -> carr. c==0 blocks also compute x0 = y0@Wy2x^T + by2x.
//  k_scan<true> : stage U -> GEMM1 -> seed = per-thread carry chain
//                 (x0 + Lambda^64-weighted carr[cc<c], R2-carry_prop op order)
//                 -> scan -> GEMM2 -> Y.
// ---------------------------------------------------------------------------
template<bool FINAL>
__global__ __launch_bounds__(256) void k_scan(
    const float* __restrict__ U, const float* __restrict__ B,
    const float* __restrict__ lr, const float* __restrict__ li,
    const float* __restrict__ W, const float* __restrict__ bx2y,
    const float* __restrict__ y0, const float* __restrict__ Wy2x,
    const float* __restrict__ by2x,
    float* __restrict__ carr, float* __restrict__ x0buf,
    float* __restrict__ Y)
{
    __shared__ short Xl[CHUNK * XP];   // 66,560 B
    __shared__ short Ul[CHUNK * UP];   //  9,216 B

    const int b  = blockIdx.x;
    const int c  = blockIdx.y;
    const int t0 = c * CHUNK;
    const int tid  = threadIdx.x;
    const int lane = tid & 63;
    const int w    = tid >> 6;          // wave 0..3
    const int lm   = lane & 15;
    const int lg   = lane >> 4;

    // ---- stage U chunk (f32 -> bf16) into Ul[t][u] ----
    {
        const int t = tid >> 2, q = (tid & 3) * 16;
        const float* up = U + ((size_t)(t0 + t) * NBATCH + b) * NUV + q;
        const float4 f0 = *(const float4*)(up + 0);
        const float4 f1 = *(const float4*)(up + 4);
        const float4 f2 = *(const float4*)(up + 8);
        const float4 f3 = *(const float4*)(up + 12);
        short8v s0, s1;
        s0[0]=(short)f2bf(f0.x); s0[1]=(short)f2bf(f0.y);
        s0[2]=(short)f2bf(f0.z); s0[3]=(short)f2bf(f0.w);
        s0[4]=(short)f2bf(f1.x); s0[5]=(short)f2bf(f1.y);
        s0[6]=(short)f2bf(f1.z); s0[7]=(short)f2bf(f1.w);
        s1[0]=(short)f2bf(f2.x); s1[1]=(short)f2bf(f2.y);
        s1[2]=(short)f2bf(f2.z); s1[3]=(short)f2bf(f2.w);
        s1[4]=(short)f2bf(f3.x); s1[5]=(short)f2bf(f3.y);
        s1[6]=(short)f2bf(f3.z); s1[7]=(short)f2bf(f3.w);
        *(short8v*)&Ul[t*UP + q]     = s0;
        *(short8v*)&Ul[t*UP + q + 8] = s1;
    }
    __syncthreads();

    // ---- GEMM1: wave w owns h'-tiles [w*8, w*8+8), all 4 t-tiles ----
    {
        bf16x8 ufrag[4][2];
        #pragma unroll
        for (int nt = 0; nt < 4; ++nt)
            #pragma unroll
            for (int ks = 0; ks < 2; ++ks)
                ufrag[nt][ks] = *(const bf16x8*)&Ul[(nt*16 + lm)*UP + lg*8 + ks*32];

        #pragma unroll
        for (int i = 0; i < 8; ++i) {
            const int mt = w*8 + i;
            const int hp = mt*16 + lm;                    // A-row h'
            const int ho = (hp >> 1) + ((hp & 1) << 8);   // orig h
            bf16x8 a[2];
            #pragma unroll
            for (int ks = 0; ks < 2; ++ks) {
                const float* bp = B + ho*NUV + lg*8 + ks*32;
                const float4 g0 = *(const float4*)(bp);
                const float4 g1 = *(const float4*)(bp + 4);
                bf16x8 t8;
                t8[0]=(short)f2bf(g0.x); t8[1]=(short)f2bf(g0.y);
                t8[2]=(short)f2bf(g0.z); t8[3]=(short)f2bf(g0.w);
                t8[4]=(short)f2bf(g1.x); t8[5]=(short)f2bf(g1.y);
                t8[6]=(short)f2bf(g1.z); t8[7]=(short)f2bf(g1.w);
                a[ks] = t8;
            }
            #pragma unroll
            for (int nt = 0; nt < 4; ++nt) {
                f32x4 acc = {0.f, 0.f, 0.f, 0.f};
                acc = __builtin_amdgcn_mfma_f32_16x16x32_bf16(a[0], ufrag[nt][0], acc, 0, 0, 0);
                acc = __builtin_amdgcn_mfma_f32_16x16x32_bf16(a[1], ufrag[nt][1], acc, 0, 0, 0);
                const int t  = nt*16 + lm;
                const int hb = mt*16 + lg*4;
                uint2 pk;
                pk.x = f2bf(acc[0]) | (f2bf(acc[1]) << 16);
                pk.y = f2bf(acc[2]) | (f2bf(acc[3]) << 16);
                *(uint2*)&Xl[t*XP + hb] = pk;
            }
        }
    }
    __syncthreads();

    // ---- scan: thread p owns complex pair (h'=2p, 2p+1) ----
    {
        const int p = tid;
        const float Lr = lr[p], Li = li[p];
        float x1, x2;
        if (FINAL) {
            // seed = carry chain (R2 carry_prop op order -> bit-identical seeds)
            const float2 x0v = *(const float2*)(x0buf + (size_t)b*NHID + 2*p);
            x1 = x0v.x; x2 = x0v.y;
            float cr = Lr, ci = Li;           // Lambda^64 by 6 squarings
            #pragma unroll
            for (int k = 0; k < 6; ++k) {
                const float nr = cr*cr - ci*ci;
                const float ni = 2.f*cr*ci;
                cr = nr; ci = ni;
            }
            for (int cc = 0; cc < c; ++cc) {
                const float2 le = *(const float2*)(carr + ((size_t)cc*NBATCH + b)*NHID + 2*p);
                const float n1 = cr*x1 - ci*x2 + le.x;
                const float n2 = ci*x1 + cr*x2 + le.y;
                x1 = n1; x2 = n2;
            }
        } else { x1 = 0.f; x2 = 0.f; }
        #pragma unroll 8
        for (int t = 0; t < CHUNK; ++t) {
            const uint d = *(const uint*)&Xl[t*XP + 2*p];
            const float n1 = fmaf(Lr, x1, fmaf(-Li, x2, bf2f_lo(d)));
            const float n2 = fmaf(Li, x1, fmaf( Lr, x2, bf2f_hi(d)));
            x1 = n1; x2 = n2;
            if (FINAL) {
                const uint pk = f2bf(x1) | (f2bf(x2) << 16);
                *(uint*)&Xl[t*XP + 2*p] = pk;
            }
        }
        if (!FINAL) {
            float2* cp = (float2*)(carr + ((size_t)c*NBATCH + b)*NHID + 2*p);
            *cp = make_float2(x1, x2);
        }
    }

    if constexpr (!FINAL) {
        // ---- x0 for batch b (c==0 blocks only) ----
        if (c == 0) {
            const int p = tid;
            float x1 = by2x[p], x2 = by2x[p + NH2];
            #pragma unroll 8
            for (int yv = 0; yv < NYV; ++yv) {
                const float y0v = y0[b * NYV + yv];
                x1 = fmaf(y0v, Wy2x[p * NYV + yv], x1);
                x2 = fmaf(y0v, Wy2x[(p + NH2) * NYV + yv], x2);
            }
            *(float2*)(x0buf + (size_t)b * NHID + 2 * p) = make_float2(x1, x2);
        }
    }

    if constexpr (FINAL) {
        __syncthreads();
        // ---- GEMM2: wave w owns y-tile w; 4 t-tiles; K = 512 ----
        const int y = w*16 + lm;
        const float bias = bx2y[y];
        f32x4 acc2[4];
        #pragma unroll
        for (int mt = 0; mt < 4; ++mt) acc2[mt] = (f32x4){bias, bias, bias, bias};

        #pragma unroll
        for (int ks = 0; ks < 16; ++ks) {
            const int p0 = lg*4 + ks*16;
            const float4 wr = *(const float4*)(W + (size_t)y*NHID + p0);
            const float4 wi = *(const float4*)(W + (size_t)y*NHID + NH2 + p0);
            bf16x8 bf;
            bf[0]=(short)f2bf(wr.x); bf[1]=(short)f2bf(wi.x);
            bf[2]=(short)f2bf(wr.y); bf[3]=(short)f2bf(wi.y);
            bf[4]=(short)f2bf(wr.z); bf[5]=(short)f2bf(wi.z);
            bf[6]=(short)f2bf(wr.w); bf[7]=(short)f2bf(wi.w);
            const int kb = lg*8 + ks*32;
            #pragma unroll
            for (int mt = 0; mt < 4; ++mt) {
                const bf16x8 xa = *(const bf16x8*)&Xl[(mt*16 + lm)*XP + kb];
                acc2[mt] = __builtin_amdgcn_mfma_f32_16x16x32_bf16(xa, bf, acc2[mt], 0, 0, 0);
            }
        }
        #pragma unroll
        for (int mt = 0; mt < 4; ++mt) {
            #pragma unroll
            for (int r = 0; r < 4; ++r) {
                const int t = mt*16 + lg*4 + r;
                Y[((size_t)(t0 + t)*NBATCH + b)*NYV + y] = acc2[mt][r];
            }
        }
    }
}

extern "C" void kernel_launch(void* const* d_in, const int* in_sizes, int n_in,
                              void* d_out, int out_size, void* d_ws, size_t ws_size,
                              hipStream_t stream) {
    const float* y0   = (const float*)d_in[0];
    const float* U    = (const float*)d_in[1];
    const float* lr   = (const float*)d_in[2];
    const float* li   = (const float*)d_in[3];
    const float* B    = (const float*)d_in[4];
    const float* Wy2x = (const float*)d_in[5];
    const float* by2x = (const float*)d_in[6];
    const float* Wx2y = (const float*)d_in[7];
    const float* bx2y = (const float*)d_in[8];
    float* Y    = (float*)d_out;
    char* ws = (char*)d_ws;
    float* carr  = (float*)(ws);                    // chunk-local end states, 2 MB
    float* x0buf = (float*)(ws + (2u<<20));         // x0 per batch, 128 KB

    dim3 grid(NBATCH, NCHUNK);
    k_scan<false><<<grid, 256, 0, stream>>>(U, B, lr, li, Wx2y, bx2y,
                                            y0, Wy2x, by2x, carr, x0buf, Y);
    k_scan<true ><<<grid, 256, 0, stream>>>(U, B, lr, li, Wx2y, bx2y,
                                            y0, Wy2x, by2x, carr, x0buf, Y);
}

// Round 16
// 65.687 us; speedup vs baseline: 1.0016x; 1.0008x over previous
//
#include <hip/hip_runtime.h>
#include <hip/hip_bf16.h>
#include <cstddef>
#include <cstdint>

#define NYV 64
#define NUV 64
#define NHID 512
#define NH2 256
#define NBATCH 64
#define CHUNK 64            // known-good geometry. CHUNK=32 poisoned (R3/R4);
                            // ALL interior mutations banned (R3/R4/R7/R11/R12:
                            // 5 failures incl. provably value-identical transforms).
#define NCHUNK 16
#define XP 520              // Xl row pitch (bf16 units) -> 1040 B, breaks pow2 stride
#define UP 72               // Ul row pitch (bf16 units) -> 144 B

typedef __attribute__((ext_vector_type(8))) short bf16x8;
typedef __attribute__((ext_vector_type(4))) float f32x4;
typedef __attribute__((ext_vector_type(8))) short short8v;

__device__ __forceinline__ uint f2bf(float f) {
    union { __hip_bfloat16 h; ushort s; } u;
    u.h = __float2bfloat16(f);
    return (uint)u.s;
}
__device__ __forceinline__ float bf2f_lo(uint d) {
    union { uint u; float f; } v; v.u = d << 16; return v.f;
}
__device__ __forceinline__ float bf2f_hi(uint d) {
    union { uint u; float f; } v; v.u = d & 0xffff0000u; return v.f;
}

// h-permutation: h' = 2p (real of pair p) / 2p+1 (imag of pair p)
// orig(h') = (h'>>1) + (h'&1)*256

// ---------------------------------------------------------------------------
// FINAL (verified: 65.5-65.8 us, absmax 0.0625, deterministic; R10/R13-R15).
// 2 dispatches, carry_prop folded in:
//  k_scan<false>: stage U -> GEMM1 -> scan from 0 -> chunk-local end states
//                 -> carr. c==0 blocks also compute x0 = y0@Wy2x^T + by2x.
//  k_scan<true> : stage U -> GEMM1 -> seed = per-thread carry chain
//                 (x0 + Lambda^64-weighted carr[cc<c], R2-carry_prop op order)
//                 -> scan -> GEMM2 -> Y.
// ---------------------------------------------------------------------------
template<bool FINAL>
__global__ __launch_bounds__(256) void k_scan(
    const float* __restrict__ U, const float* __restrict__ B,
    const float* __restrict__ lr, const float* __restrict__ li,
    const float* __restrict__ W, const float* __restrict__ bx2y,
    const float* __restrict__ y0, const float* __restrict__ Wy2x,
    const float* __restrict__ by2x,
    float* __restrict__ carr, float* __restrict__ x0buf,
    float* __restrict__ Y)
{
    __shared__ short Xl[CHUNK * XP];   // 66,560 B
    __shared__ short Ul[CHUNK * UP];   //  9,216 B

    const int b  = blockIdx.x;
    const int c  = blockIdx.y;
    const int t0 = c * CHUNK;
    const int tid  = threadIdx.x;
    const int lane = tid & 63;
    const int w    = tid >> 6;          // wave 0..3
    const int lm   = lane & 15;
    const int lg   = lane >> 4;

    // ---- stage U chunk (f32 -> bf16) into Ul[t][u] ----
    {
        const int t = tid >> 2, q = (tid & 3) * 16;
        const float* up = U + ((size_t)(t0 + t) * NBATCH + b) * NUV + q;
        const float4 f0 = *(const float4*)(up + 0);
        const float4 f1 = *(const float4*)(up + 4);
        const float4 f2 = *(const float4*)(up + 8);
        const float4 f3 = *(const float4*)(up + 12);
        short8v s0, s1;
        s0[0]=(short)f2bf(f0.x); s0[1]=(short)f2bf(f0.y);
        s0[2]=(short)f2bf(f0.z); s0[3]=(short)f2bf(f0.w);
        s0[4]=(short)f2bf(f1.x); s0[5]=(short)f2bf(f1.y);
        s0[6]=(short)f2bf(f1.z); s0[7]=(short)f2bf(f1.w);
        s1[0]=(short)f2bf(f2.x); s1[1]=(short)f2bf(f2.y);
        s1[2]=(short)f2bf(f2.z); s1[3]=(short)f2bf(f2.w);
        s1[4]=(short)f2bf(f3.x); s1[5]=(short)f2bf(f3.y);
        s1[6]=(short)f2bf(f3.z); s1[7]=(short)f2bf(f3.w);
        *(short8v*)&Ul[t*UP + q]     = s0;
        *(short8v*)&Ul[t*UP + q + 8] = s1;
    }
    __syncthreads();

    // ---- GEMM1: wave w owns h'-tiles [w*8, w*8+8), all 4 t-tiles ----
    {
        bf16x8 ufrag[4][2];
        #pragma unroll
        for (int nt = 0; nt < 4; ++nt)
            #pragma unroll
            for (int ks = 0; ks < 2; ++ks)
                ufrag[nt][ks] = *(const bf16x8*)&Ul[(nt*16 + lm)*UP + lg*8 + ks*32];

        #pragma unroll
        for (int i = 0; i < 8; ++i) {
            const int mt = w*8 + i;
            const int hp = mt*16 + lm;                    // A-row h'
            const int ho = (hp >> 1) + ((hp & 1) << 8);   // orig h
            bf16x8 a[2];
            #pragma unroll
            for (int ks = 0; ks < 2; ++ks) {
                const float* bp = B + ho*NUV + lg*8 + ks*32;
                const float4 g0 = *(const float4*)(bp);
                const float4 g1 = *(const float4*)(bp + 4);
                bf16x8 t8;
                t8[0]=(short)f2bf(g0.x); t8[1]=(short)f2bf(g0.y);
                t8[2]=(short)f2bf(g0.z); t8[3]=(short)f2bf(g0.w);
                t8[4]=(short)f2bf(g1.x); t8[5]=(short)f2bf(g1.y);
                t8[6]=(short)f2bf(g1.z); t8[7]=(short)f2bf(g1.w);
                a[ks] = t8;
            }
            #pragma unroll
            for (int nt = 0; nt < 4; ++nt) {
                f32x4 acc = {0.f, 0.f, 0.f, 0.f};
                acc = __builtin_amdgcn_mfma_f32_16x16x32_bf16(a[0], ufrag[nt][0], acc, 0, 0, 0);
                acc = __builtin_amdgcn_mfma_f32_16x16x32_bf16(a[1], ufrag[nt][1], acc, 0, 0, 0);
                const int t  = nt*16 + lm;
                const int hb = mt*16 + lg*4;
                uint2 pk;
                pk.x = f2bf(acc[0]) | (f2bf(acc[1]) << 16);
                pk.y = f2bf(acc[2]) | (f2bf(acc[3]) << 16);
                *(uint2*)&Xl[t*XP + hb] = pk;
            }
        }
    }
    __syncthreads();

    // ---- scan: thread p owns complex pair (h'=2p, 2p+1) ----
    {
        const int p = tid;
        const float Lr = lr[p], Li = li[p];
        float x1, x2;
        if (FINAL) {
            // seed = carry chain (R2 carry_prop op order -> bit-identical seeds)
            const float2 x0v = *(const float2*)(x0buf + (size_t)b*NHID + 2*p);
            x1 = x0v.x; x2 = x0v.y;
            float cr = Lr, ci = Li;           // Lambda^64 by 6 squarings
            #pragma unroll
            for (int k = 0; k < 6; ++k) {
                const float nr = cr*cr - ci*ci;
                const float ni = 2.f*cr*ci;
                cr = nr; ci = ni;
            }
            for (int cc = 0; cc < c; ++cc) {
                const float2 le = *(const float2*)(carr + ((size_t)cc*NBATCH + b)*NHID + 2*p);
                const float n1 = cr*x1 - ci*x2 + le.x;
                const float n2 = ci*x1 + cr*x2 + le.y;
                x1 = n1; x2 = n2;
            }
        } else { x1 = 0.f; x2 = 0.f; }
        #pragma unroll 8
        for (int t = 0; t < CHUNK; ++t) {
            const uint d = *(const uint*)&Xl[t*XP + 2*p];
            const float n1 = fmaf(Lr, x1, fmaf(-Li, x2, bf2f_lo(d)));
            const float n2 = fmaf(Li, x1, fmaf( Lr, x2, bf2f_hi(d)));
            x1 = n1; x2 = n2;
            if (FINAL) {
                const uint pk = f2bf(x1) | (f2bf(x2) << 16);
                *(uint*)&Xl[t*XP + 2*p] = pk;
            }
        }
        if (!FINAL) {
            float2* cp = (float2*)(carr + ((size_t)c*NBATCH + b)*NHID + 2*p);
            *cp = make_float2(x1, x2);
        }
    }

    if constexpr (!FINAL) {
        // ---- x0 for batch b (c==0 blocks only) ----
        if (c == 0) {
            const int p = tid;
            float x1 = by2x[p], x2 = by2x[p + NH2];
            #pragma unroll 8
            for (int yv = 0; yv < NYV; ++yv) {
                const float y0v = y0[b * NYV + yv];
                x1 = fmaf(y0v, Wy2x[p * NYV + yv], x1);
                x2 = fmaf(y0v, Wy2x[(p + NH2) * NYV + yv], x2);
            }
            *(float2*)(x0buf + (size_t)b * NHID + 2 * p) = make_float2(x1, x2);
        }
    }

    if constexpr (FINAL) {
        __syncthreads();
        // ---- GEMM2: wave w owns y-tile w; 4 t-tiles; K = 512 ----
        const int y = w*16 + lm;
        const float bias = bx2y[y];
        f32x4 acc2[4];
        #pragma unroll
        for (int mt = 0; mt < 4; ++mt) acc2[mt] = (f32x4){bias, bias, bias, bias};

        #pragma unroll
        for (int ks = 0; ks < 16; ++ks) {
            const int p0 = lg*4 + ks*16;
            const float4 wr = *(const float4*)(W + (size_t)y*NHID + p0);
            const float4 wi = *(const float4*)(W + (size_t)y*NHID + NH2 + p0);
            bf16x8 bf;
            bf[0]=(short)f2bf(wr.x); bf[1]=(short)f2bf(wi.x);
            bf[2]=(short)f2bf(wr.y); bf[3]=(short)f2bf(wi.y);
            bf[4]=(short)f2bf(wr.z); bf[5]=(short)f2bf(wi.z);
            bf[6]=(short)f2bf(wr.w); bf[7]=(short)f2bf(wi.w);
            const int kb = lg*8 + ks*32;
            #pragma unroll
            for (int mt = 0; mt < 4; ++mt) {
                const bf16x8 xa = *(const bf16x8*)&Xl[(mt*16 + lm)*XP + kb];
                acc2[mt] = __builtin_amdgcn_mfma_f32_16x16x32_bf16(xa, bf, acc2[mt], 0, 0, 0);
            }
        }
        #pragma unroll
        for (int mt = 0; mt < 4; ++mt) {
            #pragma unroll
            for (int r = 0; r < 4; ++r) {
                const int t = mt*16 + lg*4 + r;
                Y[((size_t)(t0 + t)*NBATCH + b)*NYV + y] = acc2[mt][r];
            }
        }
    }
}

extern "C" void kernel_launch(void* const* d_in, const int* in_sizes, int n_in,
                              void* d_out, int out_size, void* d_ws, size_t ws_size,
                              hipStream_t stream) {
    const float* y0   = (const float*)d_in[0];
    const float* U    = (const float*)d_in[1];
    const float* lr   = (const float*)d_in[2];
    const float* li   = (const float*)d_in[3];
    const float* B    = (const float*)d_in[4];
    const float* Wy2x = (const float*)d_in[5];
    const float* by2x = (const float*)d_in[6];
    const float* Wx2y = (const float*)d_in[7];
    const float* bx2y = (const float*)d_in[8];
    float* Y    = (float*)d_out;
    char* ws = (char*)d_ws;
    float* carr  = (float*)(ws);                    // chunk-local end states, 2 MB
    float* x0buf = (float*)(ws + (2u<<20));         // x0 per batch, 128 KB

    dim3 grid(NBATCH, NCHUNK);
    k_scan<false><<<grid, 256, 0, stream>>>(U, B, lr, li, Wx2y, bx2y,
                                            y0, Wy2x, by2x, carr, x0buf, Y);
    k_scan<true ><<<grid, 256, 0, stream>>>(U, B, lr, li, Wx2y, bx2y,
                                            y0, Wy2x, by2x, carr, x0buf, Y);
}

// Round 17
// 65.456 us; speedup vs baseline: 1.0051x; 1.0035x over previous
//
#include <hip/hip_runtime.h>
#include <hip/hip_bf16.h>
#include <cstddef>
#include <cstdint>

#define NYV 64
#define NUV 64
#define NHID 512
#define NH2 256
#define NBATCH 64
#define CHUNK 64            // known-good geometry. CHUNK=32 poisoned (R3/R4);
                            // ALL interior mutations banned (R3/R4/R7/R11/R12:
                            // 5 failures incl. provably value-identical transforms).
#define NCHUNK 16
#define XP 520              // Xl row pitch (bf16 units) -> 1040 B, breaks pow2 stride
#define UP 72               // Ul row pitch (bf16 units) -> 144 B

typedef __attribute__((ext_vector_type(8))) short bf16x8;
typedef __attribute__((ext_vector_type(4))) float f32x4;
typedef __attribute__((ext_vector_type(8))) short short8v;

__device__ __forceinline__ uint f2bf(float f) {
    union { __hip_bfloat16 h; ushort s; } u;
    u.h = __float2bfloat16(f);
    return (uint)u.s;
}
__device__ __forceinline__ float bf2f_lo(uint d) {
    union { uint u; float f; } v; v.u = d << 16; return v.f;
}
__device__ __forceinline__ float bf2f_hi(uint d) {
    union { uint u; float f; } v; v.u = d & 0xffff0000u; return v.f;
}

// h-permutation: h' = 2p (real of pair p) / 2p+1 (imag of pair p)
// orig(h') = (h'>>1) + (h'&1)*256

// ---------------------------------------------------------------------------
// FINAL (verified: 65.5-65.8 us, absmax 0.0625, deterministic; R10/R13-R16).
// 2 dispatches, carry_prop folded in:
//  k_scan<false>: stage U -> GEMM1 -> scan from 0 -> chunk-local end states
//                 -> carr. c==0 blocks also compute x0 = y0@Wy2x^T + by2x.
//  k_scan<true> : stage U -> GEMM1 -> seed = per-thread carry chain
//                 (x0 + Lambda^64-weighted carr[cc<c], R2-carry_prop op order)
//                 -> scan -> GEMM2 -> Y.
// ---------------------------------------------------------------------------
template<bool FINAL>
__global__ __launch_bounds__(256) void k_scan(
    const float* __restrict__ U, const float* __restrict__ B,
    const float* __restrict__ lr, const float* __restrict__ li,
    const float* __restrict__ W, const float* __restrict__ bx2y,
    const float* __restrict__ y0, const float* __restrict__ Wy2x,
    const float* __restrict__ by2x,
    float* __restrict__ carr, float* __restrict__ x0buf,
    float* __restrict__ Y)
{
    __shared__ short Xl[CHUNK * XP];   // 66,560 B
    __shared__ short Ul[CHUNK * UP];   //  9,216 B

    const int b  = blockIdx.x;
    const int c  = blockIdx.y;
    const int t0 = c * CHUNK;
    const int tid  = threadIdx.x;
    const int lane = tid & 63;
    const int w    = tid >> 6;          // wave 0..3
    const int lm   = lane & 15;
    const int lg   = lane >> 4;

    // ---- stage U chunk (f32 -> bf16) into Ul[t][u] ----
    {
        const int t = tid >> 2, q = (tid & 3) * 16;
        const float* up = U + ((size_t)(t0 + t) * NBATCH + b) * NUV + q;
        const float4 f0 = *(const float4*)(up + 0);
        const float4 f1 = *(const float4*)(up + 4);
        const float4 f2 = *(const float4*)(up + 8);
        const float4 f3 = *(const float4*)(up + 12);
        short8v s0, s1;
        s0[0]=(short)f2bf(f0.x); s0[1]=(short)f2bf(f0.y);
        s0[2]=(short)f2bf(f0.z); s0[3]=(short)f2bf(f0.w);
        s0[4]=(short)f2bf(f1.x); s0[5]=(short)f2bf(f1.y);
        s0[6]=(short)f2bf(f1.z); s0[7]=(short)f2bf(f1.w);
        s1[0]=(short)f2bf(f2.x); s1[1]=(short)f2bf(f2.y);
        s1[2]=(short)f2bf(f2.z); s1[3]=(short)f2bf(f2.w);
        s1[4]=(short)f2bf(f3.x); s1[5]=(short)f2bf(f3.y);
        s1[6]=(short)f2bf(f3.z); s1[7]=(short)f2bf(f3.w);
        *(short8v*)&Ul[t*UP + q]     = s0;
        *(short8v*)&Ul[t*UP + q + 8] = s1;
    }
    __syncthreads();

    // ---- GEMM1: wave w owns h'-tiles [w*8, w*8+8), all 4 t-tiles ----
    {
        bf16x8 ufrag[4][2];
        #pragma unroll
        for (int nt = 0; nt < 4; ++nt)
            #pragma unroll
            for (int ks = 0; ks < 2; ++ks)
                ufrag[nt][ks] = *(const bf16x8*)&Ul[(nt*16 + lm)*UP + lg*8 + ks*32];

        #pragma unroll
        for (int i = 0; i < 8; ++i) {
            const int mt = w*8 + i;
            const int hp = mt*16 + lm;                    // A-row h'
            const int ho = (hp >> 1) + ((hp & 1) << 8);   // orig h
            bf16x8 a[2];
            #pragma unroll
            for (int ks = 0; ks < 2; ++ks) {
                const float* bp = B + ho*NUV + lg*8 + ks*32;
                const float4 g0 = *(const float4*)(bp);
                const float4 g1 = *(const float4*)(bp + 4);
                bf16x8 t8;
                t8[0]=(short)f2bf(g0.x); t8[1]=(short)f2bf(g0.y);
                t8[2]=(short)f2bf(g0.z); t8[3]=(short)f2bf(g0.w);
                t8[4]=(short)f2bf(g1.x); t8[5]=(short)f2bf(g1.y);
                t8[6]=(short)f2bf(g1.z); t8[7]=(short)f2bf(g1.w);
                a[ks] = t8;
            }
            #pragma unroll
            for (int nt = 0; nt < 4; ++nt) {
                f32x4 acc = {0.f, 0.f, 0.f, 0.f};
                acc = __builtin_amdgcn_mfma_f32_16x16x32_bf16(a[0], ufrag[nt][0], acc, 0, 0, 0);
                acc = __builtin_amdgcn_mfma_f32_16x16x32_bf16(a[1], ufrag[nt][1], acc, 0, 0, 0);
                const int t  = nt*16 + lm;
                const int hb = mt*16 + lg*4;
                uint2 pk;
                pk.x = f2bf(acc[0]) | (f2bf(acc[1]) << 16);
                pk.y = f2bf(acc[2]) | (f2bf(acc[3]) << 16);
                *(uint2*)&Xl[t*XP + hb] = pk;
            }
        }
    }
    __syncthreads();

    // ---- scan: thread p owns complex pair (h'=2p, 2p+1) ----
    {
        const int p = tid;
        const float Lr = lr[p], Li = li[p];
        float x1, x2;
        if (FINAL) {
            // seed = carry chain (R2 carry_prop op order -> bit-identical seeds)
            const float2 x0v = *(const float2*)(x0buf + (size_t)b*NHID + 2*p);
            x1 = x0v.x; x2 = x0v.y;
            float cr = Lr, ci = Li;           // Lambda^64 by 6 squarings
            #pragma unroll
            for (int k = 0; k < 6; ++k) {
                const float nr = cr*cr - ci*ci;
                const float ni = 2.f*cr*ci;
                cr = nr; ci = ni;
            }
            for (int cc = 0; cc < c; ++cc) {
                const float2 le = *(const float2*)(carr + ((size_t)cc*NBATCH + b)*NHID + 2*p);
                const float n1 = cr*x1 - ci*x2 + le.x;
                const float n2 = ci*x1 + cr*x2 + le.y;
                x1 = n1; x2 = n2;
            }
        } else { x1 = 0.f; x2 = 0.f; }
        #pragma unroll 8
        for (int t = 0; t < CHUNK; ++t) {
            const uint d = *(const uint*)&Xl[t*XP + 2*p];
            const float n1 = fmaf(Lr, x1, fmaf(-Li, x2, bf2f_lo(d)));
            const float n2 = fmaf(Li, x1, fmaf( Lr, x2, bf2f_hi(d)));
            x1 = n1; x2 = n2;
            if (FINAL) {
                const uint pk = f2bf(x1) | (f2bf(x2) << 16);
                *(uint*)&Xl[t*XP + 2*p] = pk;
            }
        }
        if (!FINAL) {
            float2* cp = (float2*)(carr + ((size_t)c*NBATCH + b)*NHID + 2*p);
            *cp = make_float2(x1, x2);
        }
    }

    if constexpr (!FINAL) {
        // ---- x0 for batch b (c==0 blocks only) ----
        if (c == 0) {
            const int p = tid;
            float x1 = by2x[p], x2 = by2x[p + NH2];
            #pragma unroll 8
            for (int yv = 0; yv < NYV; ++yv) {
                const float y0v = y0[b * NYV + yv];
                x1 = fmaf(y0v, Wy2x[p * NYV + yv], x1);
                x2 = fmaf(y0v, Wy2x[(p + NH2) * NYV + yv], x2);
            }
            *(float2*)(x0buf + (size_t)b * NHID + 2 * p) = make_float2(x1, x2);
        }
    }

    if constexpr (FINAL) {
        __syncthreads();
        // ---- GEMM2: wave w owns y-tile w; 4 t-tiles; K = 512 ----
        const int y = w*16 + lm;
        const float bias = bx2y[y];
        f32x4 acc2[4];
        #pragma unroll
        for (int mt = 0; mt < 4; ++mt) acc2[mt] = (f32x4){bias, bias, bias, bias};

        #pragma unroll
        for (int ks = 0; ks < 16; ++ks) {
            const int p0 = lg*4 + ks*16;
            const float4 wr = *(const float4*)(W + (size_t)y*NHID + p0);
            const float4 wi = *(const float4*)(W + (size_t)y*NHID + NH2 + p0);
            bf16x8 bf;
            bf[0]=(short)f2bf(wr.x); bf[1]=(short)f2bf(wi.x);
            bf[2]=(short)f2bf(wr.y); bf[3]=(short)f2bf(wi.y);
            bf[4]=(short)f2bf(wr.z); bf[5]=(short)f2bf(wi.z);
            bf[6]=(short)f2bf(wr.w); bf[7]=(short)f2bf(wi.w);
            const int kb = lg*8 + ks*32;
            #pragma unroll
            for (int mt = 0; mt < 4; ++mt) {
                const bf16x8 xa = *(const bf16x8*)&Xl[(mt*16 + lm)*XP + kb];
                acc2[mt] = __builtin_amdgcn_mfma_f32_16x16x32_bf16(xa, bf, acc2[mt], 0, 0, 0);
            }
        }
        #pragma unroll
        for (int mt = 0; mt < 4; ++mt) {
            #pragma unroll
            for (int r = 0; r < 4; ++r) {
                const int t = mt*16 + lg*4 + r;
                Y[((size_t)(t0 + t)*NBATCH + b)*NYV + y] = acc2[mt][r];
            }
        }
    }
}

extern "C" void kernel_launch(void* const* d_in, const int* in_sizes, int n_in,
                              void* d_out, int out_size, void* d_ws, size_t ws_size,
                              hipStream_t stream) {
    const float* y0   = (const float*)d_in[0];
    const float* U    = (const float*)d_in[1];
    const float* lr   = (const float*)d_in[2];
    const float* li   = (const float*)d_in[3];
    const float* B    = (const float*)d_in[4];
    const float* Wy2x = (const float*)d_in[5];
    const float* by2x = (const float*)d_in[6];
    const float* Wx2y = (const float*)d_in[7];
    const float* bx2y = (const float*)d_in[8];
    float* Y    = (float*)d_out;
    char* ws = (char*)d_ws;
    float* carr  = (float*)(ws);                    // chunk-local end states, 2 MB
    float* x0buf = (float*)(ws + (2u<<20));         // x0 per batch, 128 KB

    dim3 grid(NBATCH, NCHUNK);
    k_scan<false><<<grid, 256, 0, stream>>>(U, B, lr, li, Wx2y, bx2y,
                                            y0, Wy2x, by2x, carr, x0buf, Y);
    k_scan<true ><<<grid, 256, 0, stream>>>(U, B, lr, li, Wx2y, bx2y,
                                            y0, Wy2x, by2x, carr, x0buf, Y);
}